// Round 1
// baseline (169.696 us; speedup 1.0000x reference)
//
#include <hip/hip_runtime.h>
#include <cstdint>
#include <cstddef>

typedef int v4i __attribute__((ext_vector_type(4)));

// ---------------- workspace layout (bytes) ----------------
static constexpr size_t WQ_OFF    = 0;         // 65536 int8 quantized weights
static constexpr size_t STATS_OFF = 65536;     // 512 int32: sum[256], sumsq[256]
static constexpr size_t SCALE_OFF = 67584;     // 1 uint32: bits of max|w|
static constexpr size_t AB_OFF    = 67648;     // 256 float2: per-channel affine
static constexpr size_t SBUF_OFF  = 131072;    // 16 MiB int8 s-values
static constexpr size_t WS_NEEDED = SBUF_OFF + (size_t)65536 * 256;

// ---------------- k0: zero stats + scale ----------------
__global__ void k_zero(int* stats, unsigned* scalebits) {
    int t = threadIdx.x;
    stats[t] = 0;
    stats[256 + t] = 0;
    if (t == 0) *scalebits = 0u;
}

// ---------------- k1: global max|w| ----------------
__global__ void k_maxabs(const float* __restrict__ w, unsigned* scalebits) {
    int idx = blockIdx.x * 256 + threadIdx.x;          // 64 blocks * 256 = 16384 float4
    float4 f = ((const float4*)w)[idx];
    float m = fmaxf(fmaxf(fabsf(f.x), fabsf(f.y)), fmaxf(fabsf(f.z), fabsf(f.w)));
    #pragma unroll
    for (int s = 32; s > 0; s >>= 1) m = fmaxf(m, __shfl_xor(m, s, 64));
    if ((threadIdx.x & 63) == 0) atomicMax(scalebits, __float_as_uint(m));  // all >=0: uint order ok
}

// ---------------- k2: quantize weights to int8 ----------------
__global__ void k_wquant(const float* __restrict__ w, const unsigned* __restrict__ scalebits,
                         signed char* __restrict__ wq) {
    int idx = blockIdx.x * 256 + threadIdx.x;          // 64 blocks: 16384 float4
    float scale = __uint_as_float(*scalebits) / 7.0f;  // scale_w, matches ref f32 div
    float4 f = ((const float4*)w)[idx];
    int q0 = (int)rintf(fminf(fmaxf(f.x / scale, -7.f), 7.f));
    int q1 = (int)rintf(fminf(fmaxf(f.y / scale, -7.f), 7.f));
    int q2 = (int)rintf(fminf(fmaxf(f.z / scale, -7.f), 7.f));
    int q3 = (int)rintf(fminf(fmaxf(f.w / scale, -7.f), 7.f));
    ((int*)wq)[idx] = (q0 & 255) | ((q1 & 255) << 8) | ((q2 & 255) << 16) | ((q3 & 255) << 24);
}

// ---------------- k3: main int8 MFMA GEMM + per-tile psum quant + stats ----------------
// grid 1024 x 256 threads (4 waves). Each wave owns 64 output channels (4 o-tiles of 16).
// Block processes 4 row-tiles of 16 batch rows. s = q0+q1 stored as ST (int8 or float).
template <typename ST>
__global__ __launch_bounds__(256) void k_gemm(
    const float* __restrict__ x, const signed char* __restrict__ wq,
    ST* __restrict__ sbuf, int* __restrict__ stats)
{
    __shared__ __align__(16) signed char ldsx[16 * 272];   // 16 rows x 256 k, +16B pad
    const int tid  = threadIdx.x;
    const int lane = tid & 63;
    const int wv   = tid >> 6;
    const int obase = wv * 64;
    const int lr = lane & 15, quad = lane >> 4;

    // preload weight fragments: wf[otile][ktile], B-operand layout n=lane&15, k=quad*16+j
    v4i wf[4][4];
    #pragma unroll
    for (int ot = 0; ot < 4; ++ot)
        #pragma unroll
        for (int kt = 0; kt < 4; ++kt)
            wf[ot][kt] = *(const v4i*)(wq + (size_t)(obase + ot * 16 + lr) * 256 + kt * 64 + quad * 16);

    int ssum[4] = {0, 0, 0, 0};
    int ssq[4]  = {0, 0, 0, 0};

    const int r = tid >> 4, g = tid & 15;   // staging: 16 rows x 16 lane-groups

    for (int it = 0; it < 4; ++it) {
        const int rowbase = (blockIdx.x * 4 + it) * 16;
        // ---- stage: load 16x256 fp32, quantize acts to int8 in LDS ----
        const float4* xr = (const float4*)(x + (size_t)(rowbase + r) * 256);
        #pragma unroll
        for (int j = 0; j < 4; ++j) {
            float4 f = xr[j * 16 + g];
            int b0 = (int)rintf(fminf(fmaxf(f.x, 0.f), 1.f) * 15.f);
            int b1 = (int)rintf(fminf(fmaxf(f.y, 0.f), 1.f) * 15.f);
            int b2 = (int)rintf(fminf(fmaxf(f.z, 0.f), 1.f) * 15.f);
            int b3 = (int)rintf(fminf(fmaxf(f.w, 0.f), 1.f) * 15.f);
            *(int*)(ldsx + r * 272 + j * 64 + g * 4) = b0 | (b1 << 8) | (b2 << 16) | (b3 << 24);
        }
        __syncthreads();
        // ---- A fragments: m=lane&15, k=quad*16+j ----
        v4i a[4];
        #pragma unroll
        for (int kt = 0; kt < 4; ++kt)
            a[kt] = *(const v4i*)(ldsx + lr * 272 + kt * 64 + quad * 16);
        // ---- MFMA + per-128-K-tile psum quantization ----
        #pragma unroll
        for (int ot = 0; ot < 4; ++ot) {
            v4i acc0 = {0, 0, 0, 0}, acc1 = {0, 0, 0, 0};
            acc0 = __builtin_amdgcn_mfma_i32_16x16x64_i8(a[0], wf[ot][0], acc0, 0, 0, 0);
            acc0 = __builtin_amdgcn_mfma_i32_16x16x64_i8(a[1], wf[ot][1], acc0, 0, 0, 0);
            acc1 = __builtin_amdgcn_mfma_i32_16x16x64_i8(a[2], wf[ot][2], acc1, 0, 0, 0);
            acc1 = __builtin_amdgcn_mfma_i32_16x16x64_i8(a[3], wf[ot][3], acc1, 0, 0, 0);
            const int ocol = obase + ot * 16 + lr;
            ST* sp = sbuf + (size_t)(rowbase + quad * 4) * 256 + ocol;
            #pragma unroll
            for (int e = 0; e < 4; ++e) {
                // IEEE f32 division: exact at the representable .5 ties -> rne matches jnp.round
                int q0 = (int)rintf((float)acc0[e] / 1792.0f);
                int q1 = (int)rintf((float)acc1[e] / 1792.0f);
                int s = q0 + q1;                       // in [-16,16]
                ssum[ot] += s;
                ssq[ot]  += s * s;
                sp[(size_t)e * 256] = (ST)s;
            }
        }
        __syncthreads();
    }
    // ---- per-channel stats: lanes lane, lane^16, lane^32, lane^48 share one channel ----
    #pragma unroll
    for (int ot = 0; ot < 4; ++ot) {
        int v = ssum[ot], u = ssq[ot];
        v += __shfl_xor(v, 16, 64); v += __shfl_xor(v, 32, 64);
        u += __shfl_xor(u, 16, 64); u += __shfl_xor(u, 32, 64);
        if (quad == 0) {
            atomicAdd(&stats[obase + ot * 16 + lr], v);
            atomicAdd(&stats[256 + obase + ot * 16 + lr], u);
        }
    }
}

// ---------------- k4: per-channel BN affine from exact integer stats ----------------
__global__ void k_stats(const int* __restrict__ stats, const unsigned* __restrict__ scalebits,
                        const float* __restrict__ gamma, const float* __restrict__ beta,
                        float2* __restrict__ AB)
{
    int o = threadIdx.x;
    float scale_w = __uint_as_float(*scalebits) / 7.0f;
    float t = scale_w / 15.0f;                 // ref: scale_w / qmax_a in f32
    double Cs = 1792.0 * (double)t;            // acc = s * Cs
    const double N = 65536.0;
    double mean_s = (double)stats[o] / N;
    double var_s  = (double)stats[256 + o] / N - mean_s * mean_s;
    double var    = Cs * Cs * var_s;
    double inv    = 1.0 / sqrt(var + 1e-5);
    double A = Cs * inv * (double)gamma[o];
    double B = (double)beta[o] - Cs * mean_s * inv * (double)gamma[o];
    AB[o] = make_float2((float)A, (float)B);
}

// ---------------- k5: epilogue — BN affine + clipped-ReLU quant ----------------
// 4096 blocks x 256 threads, 16 elements/thread (one 16-wide chunk of a 256-row).
template <typename LT>
__global__ __launch_bounds__(256) void k_out(const LT* sbuf, const float2* __restrict__ AB,
                                             float* out)
{
    __shared__ float2 ab[256];
    int tid = threadIdx.x;
    ab[tid] = AB[tid];
    __syncthreads();
    size_t base = ((size_t)blockIdx.x * 256 + tid) * 16;
    int o0 = (tid & 15) * 16;
    float vals[16];
    if constexpr (sizeof(LT) == 1) {
        v4i sv = *(const v4i*)((const signed char*)sbuf + base);
        #pragma unroll
        for (int j = 0; j < 4; ++j)
            #pragma unroll
            for (int e = 0; e < 4; ++e)
                vals[j * 4 + e] = (float)((sv[j] << (24 - 8 * e)) >> 24);
    } else {
        #pragma unroll
        for (int j = 0; j < 4; ++j) {
            float4 f = ((const float4*)(sbuf + base))[j];
            vals[j * 4 + 0] = f.x; vals[j * 4 + 1] = f.y;
            vals[j * 4 + 2] = f.z; vals[j * 4 + 3] = f.w;
        }
    }
    #pragma unroll
    for (int m = 0; m < 16; ++m) {
        float2 t = ab[o0 + m];
        float y = vals[m] * t.x + t.y;
        y = fminf(fmaxf(y, 0.f), 1.f) * 15.f;
        vals[m] = rintf(y) * 0.066666666666666666f;   // 1/15
    }
    float4* op = (float4*)(out + base);
    #pragma unroll
    for (int j = 0; j < 4; ++j)
        op[j] = make_float4(vals[j * 4], vals[j * 4 + 1], vals[j * 4 + 2], vals[j * 4 + 3]);
}

// ---------------- launch ----------------
extern "C" void kernel_launch(void* const* d_in, const int* in_sizes, int n_in,
                              void* d_out, int out_size, void* d_ws, size_t ws_size,
                              hipStream_t stream)
{
    const float* x     = (const float*)d_in[0];
    const float* w     = (const float*)d_in[1];
    const float* gamma = (const float*)d_in[2];
    const float* beta  = (const float*)d_in[3];
    float* out = (float*)d_out;
    char* ws = (char*)d_ws;

    signed char* wq       = (signed char*)(ws + WQ_OFF);
    int*         stats    = (int*)(ws + STATS_OFF);
    unsigned*    scalebits = (unsigned*)(ws + SCALE_OFF);
    float2*      AB       = (float2*)(ws + AB_OFF);

    k_zero<<<dim3(1), dim3(256), 0, stream>>>(stats, scalebits);
    k_maxabs<<<dim3(64), dim3(256), 0, stream>>>(w, scalebits);
    k_wquant<<<dim3(64), dim3(256), 0, stream>>>(w, scalebits, wq);

    if (ws_size >= WS_NEEDED) {
        signed char* sbuf = (signed char*)(ws + SBUF_OFF);
        k_gemm<signed char><<<dim3(1024), dim3(256), 0, stream>>>(x, wq, sbuf, stats);
        k_stats<<<dim3(1), dim3(256), 0, stream>>>(stats, scalebits, gamma, beta, AB);
        k_out<signed char><<<dim3(4096), dim3(256), 0, stream>>>(sbuf, AB, out);
    } else {
        // fallback: stage s as fp32 in d_out, finish in place
        k_gemm<float><<<dim3(1024), dim3(256), 0, stream>>>(x, wq, out, stats);
        k_stats<<<dim3(1), dim3(256), 0, stream>>>(stats, scalebits, gamma, beta, AB);
        k_out<float><<<dim3(4096), dim3(256), 0, stream>>>(out, AB, out);
    }
}

// Round 2
// 153.483 us; speedup vs baseline: 1.1056x; 1.1056x over previous
//
#include <hip/hip_runtime.h>
#include <cstdint>
#include <cstddef>

typedef int v4i __attribute__((ext_vector_type(4)));

static constexpr int NREP = 16;   // stats replica count (atomic contention spreading)

// ---------------- workspace layout (bytes) ----------------
static constexpr size_t WQ_OFF    = 0;                       // 65536 int8 quantized weights
static constexpr size_t STATS_OFF = 65536;                   // NREP * 512 int32
static constexpr size_t SCALE_OFF = STATS_OFF + NREP*512*4;  // 1 uint32 (padded)
static constexpr size_t AB_OFF    = SCALE_OFF + 64;          // 256 float2
static constexpr size_t SBUF_OFF  = 131072;                  // 16 MiB int8 s-values
static constexpr size_t WS_NEEDED = SBUF_OFF + (size_t)65536 * 256;

// exact round-half-even of p/1792 for |p| <= 13440 (1792 = 7*256)
__device__ __forceinline__ int rhe1792(int p) {
    unsigned u = (unsigned)(p + 17024);      // (p+896) + 9*1792, u in [3584,30464]
    unsigned v = u >> 8;                     // floor(u/256), in [14,119]
    unsigned d = (v * 147u) >> 10;           // floor(v/7), exact for v<=119
    int q = (int)d - 9;                      // round-half-up(p/1792)
    unsigned tie = (unsigned)((u & 255u) == 0u) & (unsigned)(v == 7u * d);
    q -= (int)(tie & ((unsigned)q & 1u));    // half-even: ties round to even
    return q;
}

// ---------------- k0: zero stats + scale ----------------
__global__ void k_zero(int* stats, unsigned* scalebits) {
    int idx = blockIdx.x * 256 + threadIdx.x;     // 32 blocks: 8192 ints
    stats[idx] = 0;
    if (idx == 0) *scalebits = 0u;
}

// ---------------- k1: global max|w| ----------------
__global__ void k_maxabs(const float* __restrict__ w, unsigned* scalebits) {
    int idx = blockIdx.x * 256 + threadIdx.x;     // 64 blocks * 256 = 16384 float4
    float4 f = ((const float4*)w)[idx];
    float m = fmaxf(fmaxf(fabsf(f.x), fabsf(f.y)), fmaxf(fabsf(f.z), fabsf(f.w)));
    #pragma unroll
    for (int s = 32; s > 0; s >>= 1) m = fmaxf(m, __shfl_xor(m, s, 64));
    if ((threadIdx.x & 63) == 0) atomicMax(scalebits, __float_as_uint(m));  // all >=0: uint order ok
}

// ---------------- k2: quantize weights to int8 ----------------
__global__ void k_wquant(const float* __restrict__ w, const unsigned* __restrict__ scalebits,
                         signed char* __restrict__ wq) {
    int idx = blockIdx.x * 256 + threadIdx.x;
    float scale = __uint_as_float(*scalebits) / 7.0f;  // scale_w, matches ref f32 div
    float4 f = ((const float4*)w)[idx];
    int q0 = (int)rintf(fminf(fmaxf(f.x / scale, -7.f), 7.f));
    int q1 = (int)rintf(fminf(fmaxf(f.y / scale, -7.f), 7.f));
    int q2 = (int)rintf(fminf(fmaxf(f.z / scale, -7.f), 7.f));
    int q3 = (int)rintf(fminf(fmaxf(f.w / scale, -7.f), 7.f));
    ((int*)wq)[idx] = (q0 & 255) | ((q1 & 255) << 8) | ((q2 & 255) << 16) | ((q3 & 255) << 24);
}

// ---------------- k3: int8 MFMA GEMM + per-tile psum quant + stats ----------------
// 1024 blocks x 256 threads (4 waves). Wave wv owns 64 output channels.
// 4 iterations of 16 batch rows; double-buffered LDS; prefetch issued post-barrier.
// __launch_bounds__(256,3): VGPR cap ~170 so wf[4][4] (64 regs) stays resident.
template <typename ST>
__global__ __launch_bounds__(256, 3) void k_gemm(
    const float* __restrict__ x, const signed char* __restrict__ wq,
    ST* __restrict__ sbuf, int* __restrict__ stats)
{
    __shared__ __align__(16) signed char ldsx[2][16 * 272];   // 2 x (16 rows x 256 k, padded)
    const int tid  = threadIdx.x;
    const int lane = tid & 63;
    const int wv   = tid >> 6;
    const int obase = wv * 64;
    const int lr = lane & 15, quad = lane >> 4;

    // weight fragments: B-operand layout n=lane&15, k=quad*16+j  (kept in VGPRs)
    v4i wf[4][4];
    #pragma unroll
    for (int ot = 0; ot < 4; ++ot)
        #pragma unroll
        for (int kt = 0; kt < 4; ++kt)
            wf[ot][kt] = *(const v4i*)(wq + (size_t)(obase + ot * 16 + lr) * 256 + kt * 64 + quad * 16);

    int ssum[4] = {0, 0, 0, 0};
    int ssq[4]  = {0, 0, 0, 0};

    const int r = tid >> 4, g = tid & 15;   // staging: 16 rows x 16 lane-groups
    const int ITER = 4;
    const size_t rb0 = (size_t)blockIdx.x * (16 * ITER);

    // prologue: load tile 0
    float4 f[4];
    {
        const float4* xr = (const float4*)(x + (rb0 + r) * 256);
        #pragma unroll
        for (int j = 0; j < 4; ++j) f[j] = xr[j * 16 + g];
    }

    for (int it = 0; it < ITER; ++it) {
        signed char* lb = ldsx[it & 1];
        // ---- quantize acts to int8, write LDS (waits on f's loads here) ----
        #pragma unroll
        for (int j = 0; j < 4; ++j) {
            int b0 = (int)rintf(fminf(fmaxf(f[j].x, 0.f), 1.f) * 15.f);
            int b1 = (int)rintf(fminf(fmaxf(f[j].y, 0.f), 1.f) * 15.f);
            int b2 = (int)rintf(fminf(fmaxf(f[j].z, 0.f), 1.f) * 15.f);
            int b3 = (int)rintf(fminf(fmaxf(f[j].w, 0.f), 1.f) * 15.f);
            *(int*)(lb + r * 272 + j * 64 + g * 4) = b0 | (b1 << 8) | (b2 << 16) | (b3 << 24);
        }
        __syncthreads();
        // ---- issue next tile's loads; consumed only at next iteration's LDS write ----
        if (it + 1 < ITER) {
            const float4* xr = (const float4*)(x + (rb0 + (it + 1) * 16 + r) * 256);
            #pragma unroll
            for (int j = 0; j < 4; ++j) f[j] = xr[j * 16 + g];
        }
        // ---- A fragments: m=lane&15, k=quad*16+j ----
        v4i a[4];
        #pragma unroll
        for (int kt = 0; kt < 4; ++kt)
            a[kt] = *(const v4i*)(lb + lr * 272 + kt * 64 + quad * 16);
        // ---- MFMA + exact per-128-K-tile psum quantization ----
        const size_t rowbase = rb0 + (size_t)it * 16;
        #pragma unroll
        for (int ot = 0; ot < 4; ++ot) {
            v4i acc0 = {0, 0, 0, 0}, acc1 = {0, 0, 0, 0};
            acc0 = __builtin_amdgcn_mfma_i32_16x16x64_i8(a[0], wf[ot][0], acc0, 0, 0, 0);
            acc0 = __builtin_amdgcn_mfma_i32_16x16x64_i8(a[1], wf[ot][1], acc0, 0, 0, 0);
            acc1 = __builtin_amdgcn_mfma_i32_16x16x64_i8(a[2], wf[ot][2], acc1, 0, 0, 0);
            acc1 = __builtin_amdgcn_mfma_i32_16x16x64_i8(a[3], wf[ot][3], acc1, 0, 0, 0);
            const int ocol = obase + ot * 16 + lr;
            ST* sp = sbuf + (rowbase + quad * 4) * 256 + ocol;
            #pragma unroll
            for (int e = 0; e < 4; ++e) {
                int s = rhe1792(acc0[e]) + rhe1792(acc1[e]);   // in [-16,16]
                ssum[ot] += s;
                ssq[ot]  += s * s;
                sp[(size_t)e * 256] = (ST)s;
            }
        }
        // next iteration's LDS write targets the other buffer; the barrier above
        // (one per iteration) is sufficient for cross-wave reuse safety.
    }
    // ---- per-channel stats into replica buffer (contention / NREP) ----
    int* st = stats + (blockIdx.x & (NREP - 1)) * 512;
    #pragma unroll
    for (int ot = 0; ot < 4; ++ot) {
        int v = ssum[ot], u = ssq[ot];
        v += __shfl_xor(v, 16, 64); v += __shfl_xor(v, 32, 64);
        u += __shfl_xor(u, 16, 64); u += __shfl_xor(u, 32, 64);
        if (quad == 0) {
            atomicAdd(&st[obase + ot * 16 + lr], v);
            atomicAdd(&st[256 + obase + ot * 16 + lr], u);
        }
    }
}

// ---------------- k4: per-channel BN affine from exact integer stats ----------------
__global__ void k_stats(const int* __restrict__ stats, const unsigned* __restrict__ scalebits,
                        const float* __restrict__ gamma, const float* __restrict__ beta,
                        float2* __restrict__ AB)
{
    int o = threadIdx.x;
    int s = 0, q = 0;
    #pragma unroll
    for (int rr = 0; rr < NREP; ++rr) {
        s += stats[rr * 512 + o];
        q += stats[rr * 512 + 256 + o];
    }
    float scale_w = __uint_as_float(*scalebits) / 7.0f;
    float t = scale_w / 15.0f;                 // ref: scale_w / qmax_a in f32
    double Cs = 1792.0 * (double)t;            // acc = s * Cs
    const double N = 65536.0;
    double mean_s = (double)s / N;
    double var_s  = (double)q / N - mean_s * mean_s;
    double var    = Cs * Cs * var_s;
    double inv    = 1.0 / sqrt(var + 1e-5);
    double A = Cs * inv * (double)gamma[o];
    double B = (double)beta[o] - Cs * mean_s * inv * (double)gamma[o];
    AB[o] = make_float2((float)A, (float)B);
}

// ---------------- k5: epilogue — BN affine + clipped-ReLU quant ----------------
template <typename LT>
__global__ __launch_bounds__(256) void k_out(const LT* sbuf, const float2* __restrict__ AB,
                                             float* out)
{
    __shared__ float2 ab[256];
    int tid = threadIdx.x;
    ab[tid] = AB[tid];
    __syncthreads();
    size_t base = ((size_t)blockIdx.x * 256 + tid) * 16;
    int o0 = (tid & 15) * 16;
    float vals[16];
    if constexpr (sizeof(LT) == 1) {
        v4i sv = *(const v4i*)((const signed char*)sbuf + base);
        #pragma unroll
        for (int j = 0; j < 4; ++j)
            #pragma unroll
            for (int e = 0; e < 4; ++e)
                vals[j * 4 + e] = (float)((sv[j] << (24 - 8 * e)) >> 24);
    } else {
        #pragma unroll
        for (int j = 0; j < 4; ++j) {
            float4 fl = ((const float4*)(sbuf + base))[j];
            vals[j * 4 + 0] = fl.x; vals[j * 4 + 1] = fl.y;
            vals[j * 4 + 2] = fl.z; vals[j * 4 + 3] = fl.w;
        }
    }
    #pragma unroll
    for (int m = 0; m < 16; ++m) {
        float2 t = ab[o0 + m];
        float y = vals[m] * t.x + t.y;
        y = fminf(fmaxf(y, 0.f), 1.f) * 15.f;
        vals[m] = rintf(y) * 0.066666666666666666f;   // 1/15
    }
    float4* op = (float4*)(out + base);
    #pragma unroll
    for (int j = 0; j < 4; ++j)
        op[j] = make_float4(vals[j * 4], vals[j * 4 + 1], vals[j * 4 + 2], vals[j * 4 + 3]);
}

// ---------------- launch ----------------
extern "C" void kernel_launch(void* const* d_in, const int* in_sizes, int n_in,
                              void* d_out, int out_size, void* d_ws, size_t ws_size,
                              hipStream_t stream)
{
    const float* x     = (const float*)d_in[0];
    const float* w     = (const float*)d_in[1];
    const float* gamma = (const float*)d_in[2];
    const float* beta  = (const float*)d_in[3];
    float* out = (float*)d_out;
    char* ws = (char*)d_ws;

    signed char* wq        = (signed char*)(ws + WQ_OFF);
    int*         stats     = (int*)(ws + STATS_OFF);
    unsigned*    scalebits = (unsigned*)(ws + SCALE_OFF);
    float2*      AB        = (float2*)(ws + AB_OFF);

    k_zero<<<dim3(32), dim3(256), 0, stream>>>(stats, scalebits);
    k_maxabs<<<dim3(64), dim3(256), 0, stream>>>(w, scalebits);
    k_wquant<<<dim3(64), dim3(256), 0, stream>>>(w, scalebits, wq);

    if (ws_size >= WS_NEEDED) {
        signed char* sbuf = (signed char*)(ws + SBUF_OFF);
        k_gemm<signed char><<<dim3(1024), dim3(256), 0, stream>>>(x, wq, sbuf, stats);
        k_stats<<<dim3(1), dim3(256), 0, stream>>>(stats, scalebits, gamma, beta, AB);
        k_out<signed char><<<dim3(4096), dim3(256), 0, stream>>>(sbuf, AB, out);
    } else {
        // fallback: stage s as fp32 in d_out, finish in place
        k_gemm<float><<<dim3(1024), dim3(256), 0, stream>>>(x, wq, out, stats);
        k_stats<<<dim3(1), dim3(256), 0, stream>>>(stats, scalebits, gamma, beta, AB);
        k_out<float><<<dim3(4096), dim3(256), 0, stream>>>(out, AB, out);
    }
}

// Round 3
// 146.395 us; speedup vs baseline: 1.1592x; 1.0484x over previous
//
#include <hip/hip_runtime.h>
#include <cstdint>
#include <cstddef>

typedef int   v4i __attribute__((ext_vector_type(4)));
typedef float v4f __attribute__((ext_vector_type(4)));

static constexpr int NREP = 16;   // stats replica count (atomic contention spreading)

// ---------------- workspace layout (bytes) ----------------
static constexpr size_t WQ_OFF    = 0;                        // 65536 int8 quantized weights
static constexpr size_t STATS_OFF = 65536;                    // NREP * 512 int32
static constexpr size_t SCALE_OFF = STATS_OFF + NREP*512*4;   // 1 uint32 (padded to 64B)
static constexpr size_t AB_OFF    = SCALE_OFF + 64;           // 256 float2
static constexpr size_t SBUF_OFF  = 131072 + 2048;            // 16 MiB int8 s-values
static constexpr size_t WS_NEEDED = SBUF_OFF + (size_t)65536 * 256;
static constexpr size_t ZERO_BYTES = NREP*512*4 + 64;         // stats + scalebits

// exact round-half-even of p/1792 for |p| <= 13440 (1792 = 7*256)
__device__ __forceinline__ int rhe1792(int p) {
    unsigned u = (unsigned)(p + 17024);      // (p+896) + 9*1792, u in [3584,30464]
    unsigned v = u >> 8;                     // floor(u/256), in [14,119]
    unsigned d = (v * 147u) >> 10;           // floor(v/7), exact for v<=119
    int q = (int)d - 9;                      // round-half-up(p/1792)
    unsigned tie = (unsigned)(((u & 255u) | (v - 7u * d)) == 0u);
    q -= (int)(tie & ((unsigned)q & 1u));    // half-even: ties round to even
    return q;
}

// ---------------- k1: global max|w| (scalebits pre-zeroed by memset) ----------------
__global__ void k_maxabs(const float* __restrict__ w, unsigned* scalebits) {
    int idx = blockIdx.x * 256 + threadIdx.x;     // 64 blocks * 256 = 16384 float4
    float4 f = ((const float4*)w)[idx];
    float m = fmaxf(fmaxf(fabsf(f.x), fabsf(f.y)), fmaxf(fabsf(f.z), fabsf(f.w)));
    #pragma unroll
    for (int s = 32; s > 0; s >>= 1) m = fmaxf(m, __shfl_xor(m, s, 64));
    if ((threadIdx.x & 63) == 0) atomicMax(scalebits, __float_as_uint(m));  // all >=0: uint order ok
}

// ---------------- k2: quantize weights to int8 ----------------
__global__ void k_wquant(const float* __restrict__ w, const unsigned* __restrict__ scalebits,
                         signed char* __restrict__ wq) {
    int idx = blockIdx.x * 256 + threadIdx.x;
    float scale = __uint_as_float(*scalebits) / 7.0f;  // scale_w, matches ref f32 div
    float4 f = ((const float4*)w)[idx];
    int q0 = (int)rintf(fminf(fmaxf(f.x / scale, -7.f), 7.f));
    int q1 = (int)rintf(fminf(fmaxf(f.y / scale, -7.f), 7.f));
    int q2 = (int)rintf(fminf(fmaxf(f.z / scale, -7.f), 7.f));
    int q3 = (int)rintf(fminf(fmaxf(f.w / scale, -7.f), 7.f));
    ((int*)wq)[idx] = (q0 & 255) | ((q1 & 255) << 8) | ((q2 & 255) << 16) | ((q3 & 255) << 24);
}

// ---------------- k3: int8 MFMA GEMM + per-tile psum quant + stats ----------------
// 1024 blocks x 256 threads (4 waves). Wave wv owns 64 output channels.
// 4 iterations of 16 batch rows; double-buffered LDS; prefetch issued post-barrier.
// __launch_bounds__(256,3): VGPR cap ~170 so wf[4][4] (64 regs) stays resident.
template <typename ST>
__global__ __launch_bounds__(256, 3) void k_gemm(
    const float* __restrict__ x, const signed char* __restrict__ wq,
    ST* __restrict__ sbuf, int* __restrict__ stats)
{
    __shared__ __align__(16) signed char ldsx[2][16 * 272];   // 2 x (16 rows x 256 k, padded)
    const int tid  = threadIdx.x;
    const int lane = tid & 63;
    const int wv   = tid >> 6;
    const int obase = wv * 64;
    const int lr = lane & 15, quad = lane >> 4;

    // weight fragments: B-operand layout n=lane&15, k=quad*16+j  (kept in VGPRs)
    v4i wf[4][4];
    #pragma unroll
    for (int ot = 0; ot < 4; ++ot)
        #pragma unroll
        for (int kt = 0; kt < 4; ++kt)
            wf[ot][kt] = *(const v4i*)(wq + (size_t)(obase + ot * 16 + lr) * 256 + kt * 64 + quad * 16);

    int ssum[4] = {0, 0, 0, 0};
    int ssq[4]  = {0, 0, 0, 0};

    const int r = tid >> 4, g = tid & 15;   // staging: 16 rows x 16 lane-groups
    const int ITER = 4;
    const size_t rb0 = (size_t)blockIdx.x * (16 * ITER);

    // prologue: load tile 0 (nontemporal: x is stream-once, keep L2 for sbuf/wq)
    v4f f[4];
    {
        const v4f* xr = (const v4f*)(x + (rb0 + r) * 256);
        #pragma unroll
        for (int j = 0; j < 4; ++j) f[j] = __builtin_nontemporal_load(&xr[j * 16 + g]);
    }

    for (int it = 0; it < ITER; ++it) {
        signed char* lb = ldsx[it & 1];
        // ---- quantize acts to int8, write LDS (waits on f's loads here) ----
        #pragma unroll
        for (int j = 0; j < 4; ++j) {
            int b0 = (int)rintf(fminf(fmaxf(f[j][0], 0.f), 1.f) * 15.f);
            int b1 = (int)rintf(fminf(fmaxf(f[j][1], 0.f), 1.f) * 15.f);
            int b2 = (int)rintf(fminf(fmaxf(f[j][2], 0.f), 1.f) * 15.f);
            int b3 = (int)rintf(fminf(fmaxf(f[j][3], 0.f), 1.f) * 15.f);
            *(int*)(lb + r * 272 + j * 64 + g * 4) = b0 | (b1 << 8) | (b2 << 16) | (b3 << 24);
        }
        __syncthreads();
        // ---- issue next tile's loads; consumed only at next iteration's LDS write ----
        if (it + 1 < ITER) {
            const v4f* xr = (const v4f*)(x + (rb0 + (it + 1) * 16 + r) * 256);
            #pragma unroll
            for (int j = 0; j < 4; ++j) f[j] = __builtin_nontemporal_load(&xr[j * 16 + g]);
        }
        // ---- A fragments: m=lane&15, k=quad*16+j ----
        v4i a[4];
        #pragma unroll
        for (int kt = 0; kt < 4; ++kt)
            a[kt] = *(const v4i*)(lb + lr * 272 + kt * 64 + quad * 16);
        // ---- MFMA + exact per-128-K-tile psum quantization ----
        const size_t rowbase = rb0 + (size_t)it * 16;
        #pragma unroll
        for (int ot = 0; ot < 4; ++ot) {
            v4i acc0 = {0, 0, 0, 0}, acc1 = {0, 0, 0, 0};
            acc0 = __builtin_amdgcn_mfma_i32_16x16x64_i8(a[0], wf[ot][0], acc0, 0, 0, 0);
            acc0 = __builtin_amdgcn_mfma_i32_16x16x64_i8(a[1], wf[ot][1], acc0, 0, 0, 0);
            acc1 = __builtin_amdgcn_mfma_i32_16x16x64_i8(a[2], wf[ot][2], acc1, 0, 0, 0);
            acc1 = __builtin_amdgcn_mfma_i32_16x16x64_i8(a[3], wf[ot][3], acc1, 0, 0, 0);
            const int ocol = obase + ot * 16 + lr;
            ST* sp = sbuf + (rowbase + quad * 4) * 256 + ocol;
            #pragma unroll
            for (int e = 0; e < 4; ++e) {
                int s = rhe1792(acc0[e]) + rhe1792(acc1[e]);   // in [-16,16]
                ssum[ot] += s;
                ssq[ot]  += s * s;
                sp[(size_t)e * 256] = (ST)s;
            }
        }
    }
    // ---- per-channel stats into replica buffer (contention / NREP) ----
    int* st = stats + (blockIdx.x & (NREP - 1)) * 512;
    #pragma unroll
    for (int ot = 0; ot < 4; ++ot) {
        int v = ssum[ot], u = ssq[ot];
        v += __shfl_xor(v, 16, 64); v += __shfl_xor(v, 32, 64);
        u += __shfl_xor(u, 16, 64); u += __shfl_xor(u, 32, 64);
        if (quad == 0) {
            atomicAdd(&st[obase + ot * 16 + lr], v);
            atomicAdd(&st[256 + obase + ot * 16 + lr], u);
        }
    }
}

// ---------------- k4: per-channel BN affine from exact integer stats ----------------
__global__ void k_stats(const int* __restrict__ stats, const unsigned* __restrict__ scalebits,
                        const float* __restrict__ gamma, const float* __restrict__ beta,
                        float2* __restrict__ AB)
{
    int o = threadIdx.x;
    int s = 0, q = 0;
    #pragma unroll
    for (int rr = 0; rr < NREP; ++rr) {
        s += stats[rr * 512 + o];
        q += stats[rr * 512 + 256 + o];
    }
    float scale_w = __uint_as_float(*scalebits) / 7.0f;
    float t = scale_w / 15.0f;                 // ref: scale_w / qmax_a in f32
    double Cs = 1792.0 * (double)t;            // acc = s * Cs
    const double N = 65536.0;
    double mean_s = (double)s / N;
    double var_s  = (double)q / N - mean_s * mean_s;
    double var    = Cs * Cs * var_s;
    double inv    = 1.0 / sqrt(var + 1e-5);
    double A = Cs * inv * (double)gamma[o];
    double B = (double)beta[o] - Cs * mean_s * inv * (double)gamma[o];
    AB[o] = make_float2((float)A, (float)B);
}

// ---------------- k5: epilogue — BN affine + clipped-ReLU quant ----------------
// 4096 blocks x 256 threads. Thread t handles 4-elem groups at flat int-index
// blk*1024 + j*256 + t  (j=0..3): loads AND stores fully coalesced (1KB/inst),
// channel group (4t)&255 constant across j. No LDS (kills 16-way bank conflict).
template <typename LT>
__global__ __launch_bounds__(256) void k_out(const LT* sbuf, const float2* __restrict__ AB,
                                             float* out)
{
    const int tid = threadIdx.x;
    const int o0 = (tid * 4) & 255;
    const float4 ab01 = *(const float4*)((const float*)AB + 2 * o0);      // A0,B0,A1,B1
    const float4 ab23 = *(const float4*)((const float*)AB + 2 * o0 + 4);  // A2,B2,A3,B3
    const size_t base = (size_t)blockIdx.x * 1024 + tid;   // 4-element-group index
    #pragma unroll
    for (int j = 0; j < 4; ++j) {
        const size_t F4 = base + (size_t)j * 256;
        float v0, v1, v2, v3;
        if constexpr (sizeof(LT) == 1) {
            int sv = ((const int*)sbuf)[F4];
            v0 = (float)((sv << 24) >> 24);
            v1 = (float)((sv << 16) >> 24);
            v2 = (float)((sv << 8) >> 24);
            v3 = (float)(sv >> 24);
        } else {
            v4f fl = ((const v4f*)sbuf)[F4];
            v0 = fl[0]; v1 = fl[1]; v2 = fl[2]; v3 = fl[3];
        }
        float y0 = rintf(fminf(fmaxf(v0 * ab01.x + ab01.y, 0.f), 1.f) * 15.f);
        float y1 = rintf(fminf(fmaxf(v1 * ab01.z + ab01.w, 0.f), 1.f) * 15.f);
        float y2 = rintf(fminf(fmaxf(v2 * ab23.x + ab23.y, 0.f), 1.f) * 15.f);
        float y3 = rintf(fminf(fmaxf(v3 * ab23.z + ab23.w, 0.f), 1.f) * 15.f);
        const float inv15 = 0.066666666666666666f;
        v4f o = { y0 * inv15, y1 * inv15, y2 * inv15, y3 * inv15 };
        __builtin_nontemporal_store(o, (v4f*)out + F4);   // out never re-read
    }
}

// ---------------- launch ----------------
extern "C" void kernel_launch(void* const* d_in, const int* in_sizes, int n_in,
                              void* d_out, int out_size, void* d_ws, size_t ws_size,
                              hipStream_t stream)
{
    const float* x     = (const float*)d_in[0];
    const float* w     = (const float*)d_in[1];
    const float* gamma = (const float*)d_in[2];
    const float* beta  = (const float*)d_in[3];
    float* out = (float*)d_out;
    char* ws = (char*)d_ws;

    signed char* wq        = (signed char*)(ws + WQ_OFF);
    int*         stats     = (int*)(ws + STATS_OFF);
    unsigned*    scalebits = (unsigned*)(ws + SCALE_OFF);
    float2*      AB        = (float2*)(ws + AB_OFF);

    hipMemsetAsync(ws + STATS_OFF, 0, ZERO_BYTES, stream);   // stats + scalebits
    k_maxabs<<<dim3(64), dim3(256), 0, stream>>>(w, scalebits);
    k_wquant<<<dim3(64), dim3(256), 0, stream>>>(w, scalebits, wq);

    if (ws_size >= WS_NEEDED) {
        signed char* sbuf = (signed char*)(ws + SBUF_OFF);
        k_gemm<signed char><<<dim3(1024), dim3(256), 0, stream>>>(x, wq, sbuf, stats);
        k_stats<<<dim3(1), dim3(256), 0, stream>>>(stats, scalebits, gamma, beta, AB);
        k_out<signed char><<<dim3(4096), dim3(256), 0, stream>>>(sbuf, AB, out);
    } else {
        // fallback: stage s as fp32 in d_out, finish in place (same-thread indices)
        k_gemm<float><<<dim3(1024), dim3(256), 0, stream>>>(x, wq, out, stats);
        k_stats<<<dim3(1), dim3(256), 0, stream>>>(stats, scalebits, gamma, beta, AB);
        k_out<float><<<dim3(4096), dim3(256), 0, stream>>>(out, AB, out);
    }
}

// Round 4
// 142.096 us; speedup vs baseline: 1.1942x; 1.0303x over previous
//
#include <hip/hip_runtime.h>
#include <cstdint>
#include <cstddef>

typedef int   v4i __attribute__((ext_vector_type(4)));
typedef float v4f __attribute__((ext_vector_type(4)));

static constexpr int NREP = 16;   // stats replica count (atomic contention spreading)

// ---------------- workspace layout (bytes) ----------------
static constexpr size_t WQ_OFF    = 0;                        // 65536 int8 quantized weights
static constexpr size_t STATS_OFF = 65536;                    // NREP * 512 int32 = 32768
static constexpr size_t PART_OFF  = STATS_OFF + NREP*512*4;   // 64 floats: per-block |w| max
static constexpr size_t AB_OFF    = PART_OFF + 256;           // 256 float2
static constexpr size_t SBUF_OFF  = 131072 + 2048;            // 16 MiB int8 s-values
static constexpr size_t WS_NEEDED = SBUF_OFF + (size_t)65536 * 256;

// exact round-half-even of p/1792 for |p| <= 13440 (1792 = 7*256)
__device__ __forceinline__ int rhe1792(int p) {
    unsigned u = (unsigned)(p + 17024);      // (p+896) + 9*1792, u in [3584,30464]
    unsigned v = u >> 8;                     // floor(u/256), in [14,119]
    unsigned d = (v * 147u) >> 10;           // floor(v/7), exact for v<=119
    int q = (int)d - 9;                      // round-half-up(p/1792)
    unsigned tie = (unsigned)(((u & 255u) | (v - 7u * d)) == 0u);
    q -= (int)(tie & ((unsigned)q & 1u));    // half-even: ties round to even
    return q;
}

// ---------------- k1: per-block max|w| partials + zero stats (no memset node) ----------------
__global__ void k_maxabs(const float* __restrict__ w, float* __restrict__ partials,
                         int* __restrict__ stats) {
    __shared__ float wmax[4];
    int idx = blockIdx.x * 256 + threadIdx.x;     // 64 blocks * 256 = 16384 float4
    float4 f = ((const float4*)w)[idx];
    float m = fmaxf(fmaxf(fabsf(f.x), fabsf(f.y)), fmaxf(fabsf(f.z), fabsf(f.w)));
    #pragma unroll
    for (int s = 32; s > 0; s >>= 1) m = fmaxf(m, __shfl_xor(m, s, 64));
    if ((threadIdx.x & 63) == 0) wmax[threadIdx.x >> 6] = m;
    if (idx < NREP * 512) stats[idx] = 0;         // 8192 slots zeroed across 64 blocks
    __syncthreads();
    if (threadIdx.x == 0)
        partials[blockIdx.x] = fmaxf(fmaxf(wmax[0], wmax[1]), fmaxf(wmax[2], wmax[3]));
}

// wave-redundant reduce of the 64 partials (L2-hot) -> global max|w|
__device__ __forceinline__ float reduce_partials(const float* __restrict__ partials, int tid) {
    float p = partials[tid & 63];
    #pragma unroll
    for (int s = 32; s > 0; s >>= 1) p = fmaxf(p, __shfl_xor(p, s, 64));
    return p;
}

// ---------------- k2: quantize weights to int8 ----------------
__global__ void k_wquant(const float* __restrict__ w, const float* __restrict__ partials,
                         signed char* __restrict__ wq) {
    int idx = blockIdx.x * 256 + threadIdx.x;
    float scale = reduce_partials(partials, threadIdx.x) / 7.0f;  // scale_w (f32 div, as ref)
    float4 f = ((const float4*)w)[idx];
    int q0 = (int)rintf(fminf(fmaxf(f.x / scale, -7.f), 7.f));
    int q1 = (int)rintf(fminf(fmaxf(f.y / scale, -7.f), 7.f));
    int q2 = (int)rintf(fminf(fmaxf(f.z / scale, -7.f), 7.f));
    int q3 = (int)rintf(fminf(fmaxf(f.w / scale, -7.f), 7.f));
    ((int*)wq)[idx] = (q0 & 255) | ((q1 & 255) << 8) | ((q2 & 255) << 16) | ((q3 & 255) << 24);
}

// ---------------- k3: int8 MFMA GEMM + per-tile psum quant + stats ----------------
// 1024 blocks x 256 threads (4 waves). One-shot staging: all 64 rows loaded with
// 16 coalesced float4 loads (deep MLP), quantized to int8 in LDS, ONE barrier,
// then a barrier-free compute phase (per wave: 16 ds_read_b128 + 64 MFMA + quant).
// __launch_bounds__(256,3): VGPR cap ~168 keeps wf[4][4] (64 regs) + 16 in-flight
// loads (64 regs) resident without spills.
template <typename ST>
__global__ __launch_bounds__(256, 3) void k_gemm(
    const float* __restrict__ x, const signed char* __restrict__ wq,
    ST* __restrict__ sbuf, int* __restrict__ stats)
{
    __shared__ __align__(16) signed char ldsx[64 * 272];   // 64 rows x 256 k (+16B pad/row)
    const int tid  = threadIdx.x;
    const int lane = tid & 63;
    const int wv   = tid >> 6;
    const int obase = wv * 64;
    const int lr = lane & 15, quad = lane >> 4;
    const size_t rb0 = (size_t)blockIdx.x * 64;

    // ---- issue all 64-row x loads (fully coalesced 4KB/inst; NT keeps L2 for sbuf/wq) ----
    v4f f[16];
    const v4f* xb = (const v4f*)(x + rb0 * 256);
    #pragma unroll
    for (int j = 0; j < 16; ++j)
        f[j] = __builtin_nontemporal_load(&xb[j * 256 + tid]);

    // ---- weight fragments (L2-hot): B-operand layout n=lane&15, k=quad*16+i ----
    v4i wf[4][4];
    #pragma unroll
    for (int ot = 0; ot < 4; ++ot)
        #pragma unroll
        for (int kt = 0; kt < 4; ++kt)
            wf[ot][kt] = *(const v4i*)(wq + (size_t)(obase + ot * 16 + lr) * 256 + kt * 64 + quad * 16);

    // ---- quantize acts to int8 -> LDS (row = j*4 + tid/64 wave-uniform; 2/bank writes) ----
    #pragma unroll
    for (int j = 0; j < 16; ++j) {
        int idx = j * 256 + tid;            // float4 flat index
        int row = idx >> 6, c = idx & 63;   // 64 float4 per row
        int b0 = (int)rintf(fminf(fmaxf(f[j][0], 0.f), 1.f) * 15.f);
        int b1 = (int)rintf(fminf(fmaxf(f[j][1], 0.f), 1.f) * 15.f);
        int b2 = (int)rintf(fminf(fmaxf(f[j][2], 0.f), 1.f) * 15.f);
        int b3 = (int)rintf(fminf(fmaxf(f[j][3], 0.f), 1.f) * 15.f);
        *(int*)(ldsx + row * 272 + c * 4) = b0 | (b1 << 8) | (b2 << 16) | (b3 << 24);
    }
    __syncthreads();   // the ONLY barrier

    int ssum[4] = {0, 0, 0, 0};
    int ssq[4]  = {0, 0, 0, 0};

    #pragma unroll
    for (int t = 0; t < 4; ++t) {
        // A fragments for row-tile t: m=lane&15, k=quad*16+i  (8 accesses/bank = b128 floor)
        v4i a[4];
        #pragma unroll
        for (int kt = 0; kt < 4; ++kt)
            a[kt] = *(const v4i*)(ldsx + (t * 16 + lr) * 272 + kt * 64 + quad * 16);
        const size_t rowbase = rb0 + (size_t)t * 16;
        #pragma unroll
        for (int ot = 0; ot < 4; ++ot) {
            v4i acc0 = {0, 0, 0, 0}, acc1 = {0, 0, 0, 0};
            acc0 = __builtin_amdgcn_mfma_i32_16x16x64_i8(a[0], wf[ot][0], acc0, 0, 0, 0);
            acc0 = __builtin_amdgcn_mfma_i32_16x16x64_i8(a[1], wf[ot][1], acc0, 0, 0, 0);
            acc1 = __builtin_amdgcn_mfma_i32_16x16x64_i8(a[2], wf[ot][2], acc1, 0, 0, 0);
            acc1 = __builtin_amdgcn_mfma_i32_16x16x64_i8(a[3], wf[ot][3], acc1, 0, 0, 0);
            const int ocol = obase + ot * 16 + lr;
            ST* sp = sbuf + (rowbase + quad * 4) * 256 + ocol;
            #pragma unroll
            for (int e = 0; e < 4; ++e) {
                int s = rhe1792(acc0[e]) + rhe1792(acc1[e]);   // exact, in [-16,16]
                ssum[ot] += s;
                ssq[ot]  += s * s;
                sp[(size_t)e * 256] = (ST)s;
            }
        }
    }
    // ---- per-channel stats into replica buffer (contention / NREP) ----
    int* st = stats + (blockIdx.x & (NREP - 1)) * 512;
    #pragma unroll
    for (int ot = 0; ot < 4; ++ot) {
        int v = ssum[ot], u = ssq[ot];
        v += __shfl_xor(v, 16, 64); v += __shfl_xor(v, 32, 64);
        u += __shfl_xor(u, 16, 64); u += __shfl_xor(u, 32, 64);
        if (quad == 0) {
            atomicAdd(&st[obase + ot * 16 + lr], v);
            atomicAdd(&st[256 + obase + ot * 16 + lr], u);
        }
    }
}

// ---------------- k4: per-channel BN affine from exact integer stats ----------------
__global__ void k_stats(const int* __restrict__ stats, const float* __restrict__ partials,
                        const float* __restrict__ gamma, const float* __restrict__ beta,
                        float2* __restrict__ AB)
{
    int o = threadIdx.x;
    int s = 0, q = 0;
    #pragma unroll
    for (int rr = 0; rr < NREP; ++rr) {
        s += stats[rr * 512 + o];
        q += stats[rr * 512 + 256 + o];
    }
    float scale_w = reduce_partials(partials, o) / 7.0f;
    float t = scale_w / 15.0f;                 // ref: scale_w / qmax_a in f32
    double Cs = 1792.0 * (double)t;            // acc = s * Cs
    const double N = 65536.0;
    double mean_s = (double)s / N;
    double var_s  = (double)q / N - mean_s * mean_s;
    double var    = Cs * Cs * var_s;
    double inv    = 1.0 / sqrt(var + 1e-5);
    double A = Cs * inv * (double)gamma[o];
    double B = (double)beta[o] - Cs * mean_s * inv * (double)gamma[o];
    AB[o] = make_float2((float)A, (float)B);
}

// ---------------- k5: epilogue — BN affine + clipped-ReLU quant ----------------
// 4096 blocks x 256 threads. Thread t handles 4-elem groups at flat int-index
// blk*1024 + j*256 + t: loads AND stores fully coalesced (1KB/inst),
// channel group (4t)&255 constant across j. No LDS.
template <typename LT>
__global__ __launch_bounds__(256) void k_out(const LT* sbuf, const float2* __restrict__ AB,
                                             float* out)
{
    const int tid = threadIdx.x;
    const int o0 = (tid * 4) & 255;
    const float4 ab01 = *(const float4*)((const float*)AB + 2 * o0);      // A0,B0,A1,B1
    const float4 ab23 = *(const float4*)((const float*)AB + 2 * o0 + 4);  // A2,B2,A3,B3
    const size_t base = (size_t)blockIdx.x * 1024 + tid;   // 4-element-group index
    #pragma unroll
    for (int j = 0; j < 4; ++j) {
        const size_t F4 = base + (size_t)j * 256;
        float v0, v1, v2, v3;
        if constexpr (sizeof(LT) == 1) {
            int sv = ((const int*)sbuf)[F4];
            v0 = (float)((sv << 24) >> 24);
            v1 = (float)((sv << 16) >> 24);
            v2 = (float)((sv << 8) >> 24);
            v3 = (float)(sv >> 24);
        } else {
            v4f fl = ((const v4f*)sbuf)[F4];
            v0 = fl[0]; v1 = fl[1]; v2 = fl[2]; v3 = fl[3];
        }
        float y0 = rintf(fminf(fmaxf(v0 * ab01.x + ab01.y, 0.f), 1.f) * 15.f);
        float y1 = rintf(fminf(fmaxf(v1 * ab01.z + ab01.w, 0.f), 1.f) * 15.f);
        float y2 = rintf(fminf(fmaxf(v2 * ab23.x + ab23.y, 0.f), 1.f) * 15.f);
        float y3 = rintf(fminf(fmaxf(v3 * ab23.z + ab23.w, 0.f), 1.f) * 15.f);
        const float inv15 = 0.066666666666666666f;
        v4f o = { y0 * inv15, y1 * inv15, y2 * inv15, y3 * inv15 };
        __builtin_nontemporal_store(o, (v4f*)out + F4);   // out never re-read
    }
}

// ---------------- launch ----------------
extern "C" void kernel_launch(void* const* d_in, const int* in_sizes, int n_in,
                              void* d_out, int out_size, void* d_ws, size_t ws_size,
                              hipStream_t stream)
{
    const float* x     = (const float*)d_in[0];
    const float* w     = (const float*)d_in[1];
    const float* gamma = (const float*)d_in[2];
    const float* beta  = (const float*)d_in[3];
    float* out = (float*)d_out;
    char* ws = (char*)d_ws;

    signed char* wq       = (signed char*)(ws + WQ_OFF);
    int*         stats    = (int*)(ws + STATS_OFF);
    float*       partials = (float*)(ws + PART_OFF);
    float2*      AB       = (float2*)(ws + AB_OFF);

    k_maxabs<<<dim3(64), dim3(256), 0, stream>>>(w, partials, stats);
    k_wquant<<<dim3(64), dim3(256), 0, stream>>>(w, partials, wq);

    if (ws_size >= WS_NEEDED) {
        signed char* sbuf = (signed char*)(ws + SBUF_OFF);
        k_gemm<signed char><<<dim3(1024), dim3(256), 0, stream>>>(x, wq, sbuf, stats);
        k_stats<<<dim3(1), dim3(256), 0, stream>>>(stats, partials, gamma, beta, AB);
        k_out<signed char><<<dim3(4096), dim3(256), 0, stream>>>(sbuf, AB, out);
    } else {
        // fallback: stage s as fp32 in d_out, finish in place (same-thread indices)
        k_gemm<float><<<dim3(1024), dim3(256), 0, stream>>>(x, wq, out, stats);
        k_stats<<<dim3(1), dim3(256), 0, stream>>>(stats, partials, gamma, beta, AB);
        k_out<float><<<dim3(4096), dim3(256), 0, stream>>>(out, AB, out);
    }
}